// Round 1
// baseline (1190.837 us; speedup 1.0000x reference)
//
#include <hip/hip_runtime.h>

#define HW 57600
#define HW2 28800
#define HW4 14400
#define BATCH 16

// workspace layout (float offsets)
#define L_OFF    0        // [2][16][16]  softmax denominators
#define AT_OFF   512      // [2][16][32][16]  A^T (folded q·Wk), [s][b][i][t]
#define CV_OFF   16896    // [2][16][16]  score constants (later minus ln L)
#define XM_OFF   17408    // [2][16][32][16]  pooled x means [s][b][i][t]
#define WVT_OFF  33792    // [2][32][16]  Wv transposed [s][i][t]

// ---- kernel 1a: adaptive-pool means over interior 4x4 blocks of 40x40 (float4) ----
__global__ void k1a_pool(const float* __restrict__ x1, const float* __restrict__ x2,
                         float* __restrict__ ws) {
  int task = blockIdx.x * 4 + (threadIdx.x >> 6);   // [0, 16384)
  int lane = threadIdx.x & 63;
  int t = task & 15, i = (task >> 4) & 31, b = (task >> 9) & 15, s = task >> 13;
  int bi = 1 + (t >> 2), bj = 1 + (t & 3);
  const float* xp = (s ? x2 : x1) + (size_t)(b * 32 + i) * HW + (40 * bi) * 240 + 40 * bj;
  float sum = 0.f;
  // 1600 px = 400 float4 (rows of 40 floats = 10 float4, 160B-aligned)
  #pragma unroll
  for (int k = 0; k < 7; ++k) {
    int e = lane + 64 * k;
    if (e < 400) {
      int r = e / 10, c = e - r * 10;
      float4 v = *(const float4*)(xp + r * 240 + c * 4);
      sum += (v.x + v.y) + (v.z + v.w);
    }
  }
  #pragma unroll
  for (int off = 32; off; off >>= 1) sum += __shfl_down(sum, off);
  if (lane == 0) ws[XM_OFF + task] = sum * (1.0f / 1600.0f);
}

// ---- kernel 1b: q = Wq*xmean+bq ; fold A^T[i][t] = sum_c q[t][c]*Wk[c][i]; cv[t]=q·bk ----
__global__ void k1b_fold(float* __restrict__ ws,
                         const float* __restrict__ Wq1, const float* __restrict__ bq1,
                         const float* __restrict__ Wq2, const float* __restrict__ bq2,
                         const float* __restrict__ Wk1, const float* __restrict__ bk1,
                         const float* __restrict__ Wk2, const float* __restrict__ bk2,
                         const float* __restrict__ Wv1, const float* __restrict__ Wv2) {
  int s = blockIdx.x >> 4, b = blockIdx.x & 15;
  const float* Wq = s ? Wq2 : Wq1;
  const float* bq = s ? bq2 : bq1;
  const float* Wk = s ? Wk1 : Wk2;   // cross: stream1 scores use Wk2, stream2 use Wk1
  const float* bk = s ? bk1 : bk2;
  __shared__ float xm[32][16];
  __shared__ float qv[16][16];
  int tid = threadIdx.x;
  for (int e = tid; e < 512; e += 256)
    xm[e >> 4][e & 15] = ws[XM_OFF + (s * 16 + b) * 512 + e];
  __syncthreads();
  {
    int t = tid >> 4, c = tid & 15;
    float acc = bq[c];
    #pragma unroll
    for (int i = 0; i < 32; ++i) acc += Wq[c * 32 + i] * xm[i][t];
    qv[t][c] = acc;
  }
  __syncthreads();
  for (int e = tid; e < 512; e += 256) {
    int i = e >> 4, t = e & 15;
    float acc = 0.f;
    #pragma unroll
    for (int c = 0; c < 16; ++c) acc += qv[t][c] * Wk[c * 32 + i];
    ws[AT_OFF + (s * 16 + b) * 512 + i * 16 + t] = acc;
  }
  if (tid < 16) {
    float acc = 0.f;
    #pragma unroll
    for (int c = 0; c < 16; ++c) acc += qv[tid][c] * bk[c];
    ws[CV_OFF + (s * 16 + b) * 16 + tid] = acc;
  }
  if (b == 0) {  // stash Wv transposed once per stream
    const float* Wv = s ? Wv2 : Wv1;
    for (int e = tid; e < 512; e += 256) {
      int i = e >> 4, t = e & 15;
      ws[WVT_OFF + s * 512 + i * 16 + t] = Wv[t * 32 + i];
    }
  }
}

// ---- kernel 2: softmax denominators L[s][b][t] = sum_n exp(A^T·x_other + cv) ----
// float4 pixels, 32 sub-blocks/slice (1024 blocks total), LDS-staged A^T, 128-VGPR cap
__global__ __launch_bounds__(256, 4)
void k2_sumexp(const float* __restrict__ x1, const float* __restrict__ x2,
               float* __restrict__ ws) {
  int slice = blockIdx.x >> 5;      // (s,b) in [0,32)
  int sub = blockIdx.x & 31;
  int s = slice >> 4, b = slice & 15;
  __shared__ float At_s[512];
  __shared__ float cv_s[16];
  __shared__ float part[4][16];
  int tid = threadIdx.x;
  {
    const float* At = ws + AT_OFF + slice * 512;
    for (int e = tid; e < 512; e += 256) At_s[e] = At[e];
    if (tid < 16) cv_s[tid] = ws[CV_OFF + slice * 16 + tid];
  }
  __syncthreads();
  const float4* xo = (const float4*)((s ? x1 : x2) + (size_t)b * 32 * HW);  // cross stream
  float La[16];
  #pragma unroll
  for (int t = 0; t < 16; ++t) La[t] = 0.f;
  for (int n = sub * 256 + tid; n < HW4; n += 32 * 256) {
    float4 sc[16];
    #pragma unroll
    for (int t = 0; t < 16; ++t) { float c = cv_s[t]; sc[t] = make_float4(c, c, c, c); }
    #pragma unroll
    for (int i = 0; i < 32; ++i) {
      float4 xi = xo[(size_t)i * HW4 + n];
      #pragma unroll
      for (int t = 0; t < 16; ++t) {
        float a = At_s[i * 16 + t];
        sc[t].x += a * xi.x; sc[t].y += a * xi.y; sc[t].z += a * xi.z; sc[t].w += a * xi.w;
      }
    }
    #pragma unroll
    for (int t = 0; t < 16; ++t)
      La[t] += (__expf(sc[t].x) + __expf(sc[t].y)) + (__expf(sc[t].z) + __expf(sc[t].w));
  }
  int w = tid >> 6, lane = tid & 63;
  #pragma unroll
  for (int t = 0; t < 16; ++t) {
    float v = La[t];
    #pragma unroll
    for (int off = 32; off; off >>= 1) v += __shfl_down(v, off);
    if (lane == 0) part[w][t] = v;
  }
  __syncthreads();
  if (tid < 16)
    atomicAdd(ws + L_OFF + slice * 16 + tid,
              (part[0][tid] + part[1][tid]) + (part[2][tid] + part[3][tid]));
}

// ---- kernel 2b: fold -ln(L) into score constants ----
__global__ void k2b_log(float* __restrict__ ws) {
  int e = threadIdx.x;  // 512 threads
  float L = ws[L_OFF + e];
  ws[CV_OFF + e] -= __logf(L);
}

// ---- kernel 3: fused per-pixel output, float2 pixels, LDS-staged weights ----
// grid (113, 16): blockIdx.y = batch (uniform per block for LDS staging)
__global__ __launch_bounds__(256, 4)
void k3_out(const float* __restrict__ x1, const float* __restrict__ x2,
            const float* __restrict__ ws,
            const float* __restrict__ Wc1, const float* __restrict__ bc1,
            const float* __restrict__ Wc2, const float* __restrict__ bc2,
            const float* __restrict__ bv1, const float* __restrict__ bv2,
            const float* __restrict__ g1p, const float* __restrict__ g2p,
            float* __restrict__ out) {
  __shared__ float At1_s[512], At2_s[512], Wv1_s[512], Wv2_s[512], Wc1_s[512], Wc2_s[512];
  __shared__ float cv1_s[16], cv2_s[16], bv1_s[16], bv2_s[16], bc1_s[32], bc2_s[32], g_s[2];
  int tid = threadIdx.x;
  int b = blockIdx.y;
  for (int e = tid; e < 512; e += 256) {
    At1_s[e] = ws[AT_OFF + b * 512 + e];
    At2_s[e] = ws[AT_OFF + 8192 + b * 512 + e];
    Wv1_s[e] = ws[WVT_OFF + e];
    Wv2_s[e] = ws[WVT_OFF + 512 + e];
    Wc1_s[e] = Wc1[e];
    Wc2_s[e] = Wc2[e];
  }
  if (tid < 16) {
    cv1_s[tid] = ws[CV_OFF + b * 16 + tid];          // includes -ln L1
    cv2_s[tid] = ws[CV_OFF + 256 + b * 16 + tid];    // includes -ln L2
    bv1_s[tid] = bv1[tid];
    bv2_s[tid] = bv2[tid];
  }
  if (tid >= 32 && tid < 64) { int o = tid - 32; bc1_s[o] = bc1[o]; bc2_s[o] = bc2[o]; }
  if (tid == 64) { g_s[0] = g1p[0]; g_s[1] = g2p[0]; }
  __syncthreads();
  int n2 = blockIdx.x * 256 + tid;                   // float2 index within image
  if (n2 >= HW2) return;                             // last block: 128 idle lanes (0.4%)
  const float2* xa = (const float2*)(x1 + (size_t)b * 32 * HW);
  const float2* xb = (const float2*)(x2 + (size_t)b * 32 * HW);
  float2* o1 = (float2*)(out + (size_t)b * 32 * HW);
  float2* o2 = (float2*)(out + (size_t)(BATCH * 32) * HW + (size_t)b * 32 * HW);
  float g1 = g_s[0], g2 = g_s[1];

  float2 sc[16], vv[16];
  // ---- stream 1: attn2 = softmax(q1·k2) over x2; out1 = x1 + g1*Wc2·(v1(x1) ⊙ attn2) ----
  #pragma unroll
  for (int t = 0; t < 16; ++t) {
    float c = cv1_s[t], v = bv1_s[t];
    sc[t] = make_float2(c, c); vv[t] = make_float2(v, v);
  }
  #pragma unroll
  for (int i = 0; i < 32; ++i) {
    float2 a  = xa[(size_t)i * HW2 + n2];
    float2 bx = xb[(size_t)i * HW2 + n2];
    #pragma unroll
    for (int t = 0; t < 16; ++t) {
      float w1 = At1_s[i * 16 + t], w2 = Wv1_s[i * 16 + t];
      sc[t].x += w1 * bx.x; sc[t].y += w1 * bx.y;
      vv[t].x += w2 * a.x;  vv[t].y += w2 * a.y;
    }
  }
  #pragma unroll
  for (int t = 0; t < 16; ++t) {
    sc[t].x = vv[t].x * __expf(sc[t].x);
    sc[t].y = vv[t].y * __expf(sc[t].y);
  }
  #pragma unroll
  for (int o = 0; o < 32; ++o) {
    float bc = bc2_s[o];
    float2 acc = make_float2(bc, bc);
    #pragma unroll
    for (int t = 0; t < 16; ++t) {
      float w = Wc2_s[o * 16 + t];
      acc.x += w * sc[t].x; acc.y += w * sc[t].y;
    }
    float2 xv = xa[(size_t)o * HW2 + n2];            // L1/L2-hot reload
    o1[(size_t)o * HW2 + n2] = make_float2(xv.x + g1 * acc.x, xv.y + g1 * acc.y);
  }
  // ---- stream 2: attn1 = softmax(q2·k1) over x1; out2 = x2 + g2*Wc1·(v2(x2) ⊙ attn1) ----
  #pragma unroll
  for (int t = 0; t < 16; ++t) {
    float c = cv2_s[t], v = bv2_s[t];
    sc[t] = make_float2(c, c); vv[t] = make_float2(v, v);
  }
  #pragma unroll
  for (int i = 0; i < 32; ++i) {
    float2 a  = xa[(size_t)i * HW2 + n2];            // L2-hot re-read
    float2 bx = xb[(size_t)i * HW2 + n2];
    #pragma unroll
    for (int t = 0; t < 16; ++t) {
      float w1 = At2_s[i * 16 + t], w2 = Wv2_s[i * 16 + t];
      sc[t].x += w1 * a.x;  sc[t].y += w1 * a.y;
      vv[t].x += w2 * bx.x; vv[t].y += w2 * bx.y;
    }
  }
  #pragma unroll
  for (int t = 0; t < 16; ++t) {
    sc[t].x = vv[t].x * __expf(sc[t].x);
    sc[t].y = vv[t].y * __expf(sc[t].y);
  }
  #pragma unroll
  for (int o = 0; o < 32; ++o) {
    float bc = bc1_s[o];
    float2 acc = make_float2(bc, bc);
    #pragma unroll
    for (int t = 0; t < 16; ++t) {
      float w = Wc1_s[o * 16 + t];
      acc.x += w * sc[t].x; acc.y += w * sc[t].y;
    }
    float2 xv = xb[(size_t)o * HW2 + n2];
    o2[(size_t)o * HW2 + n2] = make_float2(xv.x + g2 * acc.x, xv.y + g2 * acc.y);
  }
}

extern "C" void kernel_launch(void* const* d_in, const int* in_sizes, int n_in,
                              void* d_out, int out_size, void* d_ws, size_t ws_size,
                              hipStream_t stream) {
  const float* x1  = (const float*)d_in[0];
  const float* x2  = (const float*)d_in[1];
  const float* Wq1 = (const float*)d_in[2];  const float* bq1 = (const float*)d_in[3];
  const float* Wk1 = (const float*)d_in[4];  const float* bk1 = (const float*)d_in[5];
  const float* Wv1 = (const float*)d_in[6];  const float* bv1 = (const float*)d_in[7];
  const float* Wq2 = (const float*)d_in[8];  const float* bq2 = (const float*)d_in[9];
  const float* Wk2 = (const float*)d_in[10]; const float* bk2 = (const float*)d_in[11];
  const float* Wv2 = (const float*)d_in[12]; const float* bv2 = (const float*)d_in[13];
  const float* Wc1 = (const float*)d_in[14]; const float* bc1 = (const float*)d_in[15];
  const float* Wc2 = (const float*)d_in[16]; const float* bc2 = (const float*)d_in[17];
  const float* g1  = (const float*)d_in[18]; const float* g2  = (const float*)d_in[19];
  float* out = (float*)d_out;
  float* ws  = (float*)d_ws;

  hipMemsetAsync(d_ws, 0, 512 * sizeof(float), stream);           // zero L accumulators
  k1a_pool<<<4096, 256, 0, stream>>>(x1, x2, ws);
  k1b_fold<<<32, 256, 0, stream>>>(ws, Wq1, bq1, Wq2, bq2, Wk1, bk1, Wk2, bk2, Wv1, Wv2);
  k2_sumexp<<<1024, 256, 0, stream>>>(x1, x2, ws);
  k2b_log<<<1, 512, 0, stream>>>(ws);
  k3_out<<<dim3(113, 16), 256, 0, stream>>>(x1, x2, ws, Wc1, bc1, Wc2, bc2, bv1, bv2, g1, g2, out);
}